// Round 12
// baseline (245.422 us; speedup 1.0000x reference)
//
#include <hip/hip_runtime.h>

#define NN 24
#define POWER_ITERS 30
#define FISTA_ITERS 200

// All cross-lane traffic on the VALU pipe via DPP (R8: DS pipe was the
// 176-212us floor). 8-lane groups: G = 72 floats/lane. R11 proved plain VALU
// CANNOT source AGPRs on gfx950 (assembler rejects) -> G must be in ARCH
// VGPRs. This round: waves_per_eu(1,1) (largest observed arch grant, 132 in
// R9) + chunked phase-1 (peak pressure ~86 < 132) so the allocator has no
// reason to touch AGPRs at all.
template<int CTRL>
__device__ __forceinline__ float dpp(float v) {
    return __int_as_float(__builtin_amdgcn_update_dpp(
        0, __float_as_int(v), CTRL, 0xF, 0xF, true));
}
// quad broadcasts: quad_perm[L,L,L,L]
#define BC0(x) dpp<0x00>(x)
#define BC1(x) dpp<0x55>(x)
#define BC2(x) dpp<0xAA>(x)
#define BC3(x) dpp<0xFF>(x)
// quad xor butterflies
#define QX1(x) dpp<0xB1>(x)            // lane ^= 1
#define QX2(x) dpp<0x4E>(x)            // lane ^= 2
#define QX3(x) dpp<0x1B>(x)            // lane ^= 3
#define HMIR(x) dpp<0x141>(x)          // ROW_HALF_MIRROR: lane ^= 7 (8-group)
#define XOR4(x) HMIR(QX3(x))           // (^3 then ^7) = lane ^= 4 (8-group)

// Lane ls (=tid&7) owns cone ls: rows {ls, 8+2ls, 9+2ls} of G.
// y slots: s0=y[ls], s1=y[8+2ls], s2=y[9+2ls].
// G rows stored COLUMN-PERMUTED per lane (p = quad parity = ls>>2):
//   pos 0-3   <- t-cols of my quad     (4p..4p+3)
//   pos 4-7   <- t-cols of other quad
//   pos 8-15  <- x-cols of my quad     (8+8p..15+8p)
//   pos 16-23 <- x-cols of other quad
// so broadcasts map positionally identically for both quads. (R10-verified.)
#define MV(jp, e) { const float vj = (e);                                      \
    g0 = fmaf(GR0[jp], vj, g0); g1 = fmaf(GR1[jp], vj, g1);                    \
    g2 = fmaf(GR2[jp], vj, g2); }
#define MATVEC(s0, s1, s2) do {                                                \
    const float s0x = XOR4(s0), s1x = XOR4(s1), s2x = XOR4(s2);                \
    MV(0,  BC0(s0))  MV(1,  BC1(s0))  MV(2,  BC2(s0))  MV(3,  BC3(s0))        \
    MV(4,  BC0(s0x)) MV(5,  BC1(s0x)) MV(6,  BC2(s0x)) MV(7,  BC3(s0x))       \
    MV(8,  BC0(s1))  MV(9,  BC0(s2))  MV(10, BC1(s1))  MV(11, BC1(s2))        \
    MV(12, BC2(s1))  MV(13, BC2(s2))  MV(14, BC3(s1))  MV(15, BC3(s2))        \
    MV(16, BC0(s1x)) MV(17, BC0(s2x)) MV(18, BC1(s1x)) MV(19, BC1(s2x))       \
    MV(20, BC2(s1x)) MV(21, BC2(s2x)) MV(22, BC3(s1x)) MV(23, BC3(s2x))       \
} while (0)

// Phase-1 chunk: consume one float4 of the (permuted) row immediately —
// no row[24] staging, keeps peak pressure ~86 floats.
#define P1CHUNK(baseptr, off) do {                                             \
    const float4 r_ = *reinterpret_cast<const float4*>(baseptr);               \
    GR0[off + 0] = fmaf(a0,   r_.x, GR0[off + 0]);                             \
    GR0[off + 1] = fmaf(a0,   r_.y, GR0[off + 1]);                             \
    GR0[off + 2] = fmaf(a0,   r_.z, GR0[off + 2]);                             \
    GR0[off + 3] = fmaf(a0,   r_.w, GR0[off + 3]);                             \
    GR1[off + 0] = fmaf(ax.x, r_.x, GR1[off + 0]);                             \
    GR1[off + 1] = fmaf(ax.x, r_.y, GR1[off + 1]);                             \
    GR1[off + 2] = fmaf(ax.x, r_.z, GR1[off + 2]);                             \
    GR1[off + 3] = fmaf(ax.x, r_.w, GR1[off + 3]);                             \
    GR2[off + 0] = fmaf(ax.y, r_.x, GR2[off + 0]);                             \
    GR2[off + 1] = fmaf(ax.y, r_.y, GR2[off + 1]);                             \
    GR2[off + 2] = fmaf(ax.y, r_.z, GR2[off + 2]);                             \
    GR2[off + 3] = fmaf(ax.y, r_.w, GR2[off + 3]);                             \
} while (0)

__global__ __attribute__((amdgpu_waves_per_eu(1, 1))) void __launch_bounds__(256, 1)
qcqp_kernel(const float* __restrict__ P, const float* __restrict__ qv,
            float* __restrict__ out, int Btot) {
    const int tid = blockIdx.x * blockDim.x + threadIdx.x;
    const int b = tid >> 3;
    if (b >= Btot) return;
    const int ls = tid & 7;        // lane-in-8-group; owns cone ls
    const int p  = ls >> 2;        // quad parity within the 8-group
    const int rx = 8 + 2 * ls;     // own x rows: rx, rx+1

    // permuted column bases (all float4-aligned)
    const int tA = 4 * p, tB = 4 - 4 * p;       // pos 0-3, 4-7
    const int xA = 8 + 8 * p, xB = 16 - 8 * p;  // pos 8-15, 16-23

    const float* __restrict__ Pb = P + (size_t)b * (NN * NN);
    const float* __restrict__ qb = qv + (size_t)b * NN;

    // ---- Phase 1: own 3 rows of G = P^T P (REG=1e-7 dropped: ~3e-8 rel),
    //      column-permuted; bb = -(P^T q) own rows ----
    float GR0[NN], GR1[NN], GR2[NN];
#pragma unroll
    for (int j = 0; j < NN; ++j) { GR0[j] = 0.f; GR1[j] = 0.f; GR2[j] = 0.f; }
    float bb0 = 0.f, bb1 = 0.f, bb2 = 0.f;

#pragma unroll 1
    for (int k = 0; k < NN; ++k) {
        const float* rp = Pb + k * NN;
        const float  a0 = rp[ls];                                    // A[k][ls]
        const float2 ax = *reinterpret_cast<const float2*>(rp + rx); // A[k][8+2ls..]
        const float  qk = qb[k];
        bb0 = fmaf(-a0,   qk, bb0);
        bb1 = fmaf(-ax.x, qk, bb1);
        bb2 = fmaf(-ax.y, qk, bb2);
        P1CHUNK(rp + tA,     0);
        P1CHUNK(rp + tB,     4);
        P1CHUNK(rp + xA,     8);
        P1CHUNK(rp + xA + 4, 12);
        P1CHUNK(rp + xB,     16);
        P1CHUNK(rp + xB + 4, 20);
    }

    // ---- Phase 2: power iteration -> step = 1/(L + 1e-12) ----
    float vo0 = 0.20412414523193150818f;  // 1/sqrt(24)
    float vo1 = vo0, vo2 = vo0;

#pragma unroll 1
    for (int it = 0; it < POWER_ITERS; ++it) {
        float g0 = 0.f, g1 = 0.f, g2 = 0.f;
        MATVEC(vo0, vo1, vo2);
        float n2 = fmaf(g0, g0, fmaf(g1, g1, g2 * g2));
        n2 += QX1(n2);
        n2 += QX2(n2);
        n2 += XOR4(n2);
        const float inv = __builtin_amdgcn_rsqf(fmaxf(n2, 1e-60f));
        vo0 = g0 * inv; vo1 = g1 * inv; vo2 = g2 * inv;
    }
    float step;
    {
        float g0 = 0.f, g1 = 0.f, g2 = 0.f;
        MATVEC(vo0, vo1, vo2);
        float Lp = fmaf(vo0, g0, fmaf(vo1, g1, vo2 * g2));
        Lp += QX1(Lp);
        Lp += QX2(Lp);
        Lp += XOR4(Lp);
        step = __builtin_amdgcn_rcpf(Lp + 1e-12f);
    }
    const float nstep = -step;

    // ---- Phase 3: FISTA ----
    float yo0 = 0.f, yo1 = 0.f, yo2 = 0.f;
    float lo0 = 0.f, lo1 = 0.f, lo2 = 0.f;
    float tk = 1.f;

#pragma unroll 1
    for (int it = 0; it < FISTA_ITERS; ++it) {
        float g0 = bb0, g1 = bb1, g2 = bb2;
        MATVEC(yo0, yo1, yo2);
        const float t  = fmaf(nstep, g0, yo0);
        const float x1 = fmaf(nstep, g1, yo1);
        const float x2 = fmaf(nstep, g2, yo2);
        // SOC projection (lane-local: lane owns exactly cone ls)
        const float nx    = __builtin_amdgcn_sqrtf(fmaf(x1, x1, x2 * x2));
        const float alpha = 0.5f * (t + nx);
        const bool inside = (nx <= t);
        const bool zero_  = (nx <= -t);
        const float ln0 = inside ? t : (zero_ ? 0.f : alpha);
        const float sc  = inside ? 1.f
                                 : (zero_ ? 0.f
                                          : alpha * __builtin_amdgcn_rcpf(fmaxf(nx, 1e-12f)));
        const float ln1 = x1 * sc;
        const float ln2 = x2 * sc;
        const float tkn = 0.5f * (1.f + __builtin_amdgcn_sqrtf(fmaf(4.f * tk, tk, 1.f)));
        const float bet = (tk - 1.f) * __builtin_amdgcn_rcpf(tkn);
        tk = tkn;
        yo0 = fmaf(bet, ln0 - lo0, ln0); lo0 = ln0;
        yo1 = fmaf(bet, ln1 - lo1, ln1); lo1 = ln1;
        yo2 = fmaf(bet, ln2 - lo2, ln2); lo2 = ln2;
    }

    // ---- store own components (disjoint across the 8-group, covers all 24) ----
    float* ob = out + (size_t)b * NN;
    ob[ls] = lo0;
    *reinterpret_cast<float2*>(ob + rx) = make_float2(lo1, lo2);
}

extern "C" void kernel_launch(void* const* d_in, const int* in_sizes, int n_in,
                              void* d_out, int out_size, void* d_ws, size_t ws_size,
                              hipStream_t stream) {
    const float* P = (const float*)d_in[0];
    const float* q = (const float*)d_in[1];
    float* out = (float*)d_out;
    const int Btot = in_sizes[0] / (NN * NN);
    const long long threads = 8LL * Btot;
    const int block = 256;
    const int grid = (int)((threads + block - 1) / block);
    qcqp_kernel<<<grid, block, 0, stream>>>(P, q, out, Btot);
}

// Round 13
// 201.746 us; speedup vs baseline: 1.2165x; 1.2165x over previous
//
#include <hip/hip_runtime.h>

#define NN 24
#define POWER_ITERS 30
#define FISTA_ITERS 200

// Cross-lane via v_mov_b32_dpp WITHOUT the tied-old operand.
// R12 lesson: __builtin_amdgcn_update_dpp(0, src, ...) forces a zero-init
// v_mov into the tied dest before EVERY dpp (~30 extra instr/iter in the
// matvec = the measured 248-vs-137 gap). All lanes in a group are always
// active here, so old is dead -> __builtin_amdgcn_mov_dpp (bound_ctrl=1).
template<int CTRL>
__device__ __forceinline__ float dpp(float v) {
    return __int_as_float(__builtin_amdgcn_mov_dpp(
        __float_as_int(v), CTRL, 0xF, 0xF, true));
}
// quad broadcasts: quad_perm[L,L,L,L]
#define BC0(x) dpp<0x00>(x)
#define BC1(x) dpp<0x55>(x)
#define BC2(x) dpp<0xAA>(x)
#define BC3(x) dpp<0xFF>(x)
// quad xor butterflies
#define QX1(x) dpp<0xB1>(x)            // lane ^= 1
#define QX2(x) dpp<0x4E>(x)            // lane ^= 2
#define QX3(x) dpp<0x1B>(x)            // lane ^= 3
#define HMIR(x) dpp<0x141>(x)          // ROW_HALF_MIRROR: lane ^= 7 (8-group)
#define XOR4(x) HMIR(QX3(x))           // (^3 then ^7) = lane ^= 4 (8-group)

// Lane ls (=tid&7) owns cone ls: rows {ls, 8+2ls, 9+2ls} of G.
// y slots: s0=y[ls], s1=y[8+2ls], s2=y[9+2ls].
// G rows stored COLUMN-PERMUTED per lane (p = quad parity = ls>>2):
//   pos 0-3   <- t-cols of my quad     (4p..4p+3)
//   pos 4-7   <- t-cols of other quad
//   pos 8-15  <- x-cols of my quad     (8+8p..15+8p)
//   pos 16-23 <- x-cols of other quad
// so broadcasts map positionally identically for both quads. (R10-verified.)
#define MV(jp, e) { const float vj = (e);                                      \
    g0 = fmaf(GR0[jp], vj, g0); g1 = fmaf(GR1[jp], vj, g1);                    \
    g2 = fmaf(GR2[jp], vj, g2); }
#define MATVEC(s0, s1, s2) do {                                                \
    const float s0x = XOR4(s0), s1x = XOR4(s1), s2x = XOR4(s2);                \
    MV(0,  BC0(s0))  MV(1,  BC1(s0))  MV(2,  BC2(s0))  MV(3,  BC3(s0))        \
    MV(4,  BC0(s0x)) MV(5,  BC1(s0x)) MV(6,  BC2(s0x)) MV(7,  BC3(s0x))       \
    MV(8,  BC0(s1))  MV(9,  BC0(s2))  MV(10, BC1(s1))  MV(11, BC1(s2))        \
    MV(12, BC2(s1))  MV(13, BC2(s2))  MV(14, BC3(s1))  MV(15, BC3(s2))        \
    MV(16, BC0(s1x)) MV(17, BC0(s2x)) MV(18, BC1(s1x)) MV(19, BC1(s2x))       \
    MV(20, BC2(s1x)) MV(21, BC2(s2x)) MV(22, BC3(s1x)) MV(23, BC3(s2x))       \
} while (0)

// Phase-1 chunk: consume one float4 of the (permuted) row immediately —
// no row[24] staging, keeps peak pressure ~86 floats.
#define P1CHUNK(baseptr, off) do {                                             \
    const float4 r_ = *reinterpret_cast<const float4*>(baseptr);               \
    GR0[off + 0] = fmaf(a0,   r_.x, GR0[off + 0]);                             \
    GR0[off + 1] = fmaf(a0,   r_.y, GR0[off + 1]);                             \
    GR0[off + 2] = fmaf(a0,   r_.z, GR0[off + 2]);                             \
    GR0[off + 3] = fmaf(a0,   r_.w, GR0[off + 3]);                             \
    GR1[off + 0] = fmaf(ax.x, r_.x, GR1[off + 0]);                             \
    GR1[off + 1] = fmaf(ax.x, r_.y, GR1[off + 1]);                             \
    GR1[off + 2] = fmaf(ax.x, r_.z, GR1[off + 2]);                             \
    GR1[off + 3] = fmaf(ax.x, r_.w, GR1[off + 3]);                             \
    GR2[off + 0] = fmaf(ax.y, r_.x, GR2[off + 0]);                             \
    GR2[off + 1] = fmaf(ax.y, r_.y, GR2[off + 1]);                             \
    GR2[off + 2] = fmaf(ax.y, r_.z, GR2[off + 2]);                             \
    GR2[off + 3] = fmaf(ax.y, r_.w, GR2[off + 3]);                             \
} while (0)

// waves_per_eu(1,2): the config whose arch grant (88-104, R8/R10) covers the
// ~86-float pressure, while keeping 2 resident waves to hide phase-1 /
// transcendental latency ((1,1) in R12 dropped to 0.9 waves and stalled).
__global__ __attribute__((amdgpu_waves_per_eu(1, 2))) void __launch_bounds__(256, 1)
qcqp_kernel(const float* __restrict__ P, const float* __restrict__ qv,
            float* __restrict__ out, int Btot) {
    const int tid = blockIdx.x * blockDim.x + threadIdx.x;
    const int b = tid >> 3;
    if (b >= Btot) return;
    const int ls = tid & 7;        // lane-in-8-group; owns cone ls
    const int p  = ls >> 2;        // quad parity within the 8-group
    const int rx = 8 + 2 * ls;     // own x rows: rx, rx+1

    // permuted column bases (all float4-aligned)
    const int tA = 4 * p, tB = 4 - 4 * p;       // pos 0-3, 4-7
    const int xA = 8 + 8 * p, xB = 16 - 8 * p;  // pos 8-15, 16-23

    const float* __restrict__ Pb = P + (size_t)b * (NN * NN);
    const float* __restrict__ qb = qv + (size_t)b * NN;

    // ---- Phase 1: own 3 rows of G = P^T P (REG=1e-7 dropped: ~3e-8 rel),
    //      column-permuted; bb = -(P^T q) own rows ----
    float GR0[NN], GR1[NN], GR2[NN];
#pragma unroll
    for (int j = 0; j < NN; ++j) { GR0[j] = 0.f; GR1[j] = 0.f; GR2[j] = 0.f; }
    float bb0 = 0.f, bb1 = 0.f, bb2 = 0.f;

#pragma unroll 1
    for (int k = 0; k < NN; ++k) {
        const float* rp = Pb + k * NN;
        const float  a0 = rp[ls];                                    // A[k][ls]
        const float2 ax = *reinterpret_cast<const float2*>(rp + rx); // A[k][8+2ls..]
        const float  qk = qb[k];
        bb0 = fmaf(-a0,   qk, bb0);
        bb1 = fmaf(-ax.x, qk, bb1);
        bb2 = fmaf(-ax.y, qk, bb2);
        P1CHUNK(rp + tA,     0);
        P1CHUNK(rp + tB,     4);
        P1CHUNK(rp + xA,     8);
        P1CHUNK(rp + xA + 4, 12);
        P1CHUNK(rp + xB,     16);
        P1CHUNK(rp + xB + 4, 20);
    }

    // ---- Phase 2: power iteration -> step = 1/(L + 1e-12) ----
    float vo0 = 0.20412414523193150818f;  // 1/sqrt(24)
    float vo1 = vo0, vo2 = vo0;

#pragma unroll 1
    for (int it = 0; it < POWER_ITERS; ++it) {
        float g0 = 0.f, g1 = 0.f, g2 = 0.f;
        MATVEC(vo0, vo1, vo2);
        float n2 = fmaf(g0, g0, fmaf(g1, g1, g2 * g2));
        n2 += QX1(n2);
        n2 += QX2(n2);
        n2 += XOR4(n2);
        const float inv = __builtin_amdgcn_rsqf(fmaxf(n2, 1e-60f));
        vo0 = g0 * inv; vo1 = g1 * inv; vo2 = g2 * inv;
    }
    float step;
    {
        float g0 = 0.f, g1 = 0.f, g2 = 0.f;
        MATVEC(vo0, vo1, vo2);
        float Lp = fmaf(vo0, g0, fmaf(vo1, g1, vo2 * g2));
        Lp += QX1(Lp);
        Lp += QX2(Lp);
        Lp += XOR4(Lp);
        step = __builtin_amdgcn_rcpf(Lp + 1e-12f);
    }
    const float nstep = -step;

    // ---- Phase 3: FISTA ----
    float yo0 = 0.f, yo1 = 0.f, yo2 = 0.f;
    float lo0 = 0.f, lo1 = 0.f, lo2 = 0.f;
    float tk = 1.f;

#pragma unroll 1
    for (int it = 0; it < FISTA_ITERS; ++it) {
        float g0 = bb0, g1 = bb1, g2 = bb2;
        MATVEC(yo0, yo1, yo2);
        const float t  = fmaf(nstep, g0, yo0);
        const float x1 = fmaf(nstep, g1, yo1);
        const float x2 = fmaf(nstep, g2, yo2);
        // SOC projection (lane-local: lane owns exactly cone ls)
        const float nx    = __builtin_amdgcn_sqrtf(fmaf(x1, x1, x2 * x2));
        const float alpha = 0.5f * (t + nx);
        const bool inside = (nx <= t);
        const bool zero_  = (nx <= -t);
        const float ln0 = inside ? t : (zero_ ? 0.f : alpha);
        const float sc  = inside ? 1.f
                                 : (zero_ ? 0.f
                                          : alpha * __builtin_amdgcn_rcpf(fmaxf(nx, 1e-12f)));
        const float ln1 = x1 * sc;
        const float ln2 = x2 * sc;
        const float tkn = 0.5f * (1.f + __builtin_amdgcn_sqrtf(fmaf(4.f * tk, tk, 1.f)));
        const float bet = (tk - 1.f) * __builtin_amdgcn_rcpf(tkn);
        tk = tkn;
        yo0 = fmaf(bet, ln0 - lo0, ln0); lo0 = ln0;
        yo1 = fmaf(bet, ln1 - lo1, ln1); lo1 = ln1;
        yo2 = fmaf(bet, ln2 - lo2, ln2); lo2 = ln2;
    }

    // ---- store own components (disjoint across the 8-group, covers all 24) ----
    float* ob = out + (size_t)b * NN;
    ob[ls] = lo0;
    *reinterpret_cast<float2*>(ob + rx) = make_float2(lo1, lo2);
}

extern "C" void kernel_launch(void* const* d_in, const int* in_sizes, int n_in,
                              void* d_out, int out_size, void* d_ws, size_t ws_size,
                              hipStream_t stream) {
    const float* P = (const float*)d_in[0];
    const float* q = (const float*)d_in[1];
    float* out = (float*)d_out;
    const int Btot = in_sizes[0] / (NN * NN);
    const long long threads = 8LL * Btot;
    const int block = 256;
    const int grid = (int)((threads + block - 1) / block);
    qcqp_kernel<<<grid, block, 0, stream>>>(P, q, out, Btot);
}